// Round 3
// baseline (251.999 us; speedup 1.0000x reference)
//
#include <hip/hip_runtime.h>
#include <hip/hip_bf16.h>
#include <math.h>
#include <stdint.h>

// DiverseSiblingsSearch (lprobs (128,5,50257) f32, scores (128,5,10) f32, step=10)
//   lp = lprobs + scores[:,:,step-1,None]  (bias added BEFORE all ordering, as reference)
//   per (b,beam): top-10 of lp over vocab; penalty -0.5*(rank+1); per b: top-10 of 50.
// Outputs concat as float32 values: scores[1280] | indices[1280] | beams[1280]
//
// Kernel 1 (dss_chunk_topk): grid (nc chunks, 640 rows). Per block:
//   pass1: stream chunk from HBM -> LDS (biased), per-thread max.
//   tau  : 10th largest of the 256 thread maxes (valid lower bound on chunk's
//          10th-largest; guarantees >=10 survivors, <=10*ceil(cs/256) survivors).
//   pass2: filter LDS >= tau -> candidate list; one wave extracts exact top-10
//          (key = ford(val)<<32 | ~idx : value desc, index asc — jax tie order).
// Kernel 2 (dss_final): per b, 5 waves merge each row's nc*10 candidates ->
//   row top-10 -> rank penalty -> wave 0 does final top-10 of 50 (flat-pos tie).

#define BS   256
#define KK   10
#define BEAM 5
#define CAP  512    // survivors/chunk <= 10*ceil(6283/256)=250 (+tie headroom)
#define FCAP 2048   // fallback (whole-row) survivor cap

typedef unsigned long long u64;

// monotone float <-> uint map (no NaNs in log_softmax output)
__device__ __forceinline__ uint32_t ford(float x) {
    uint32_t u = __float_as_uint(x);
    return (u & 0x80000000u) ? ~u : (u | 0x80000000u);
}
__device__ __forceinline__ float funord(uint32_t u) {
    return __uint_as_float((u & 0x80000000u) ? (u & 0x7fffffffu) : ~u);
}

// guarded sorted-desc insert (common path: 1 compare)
__device__ __forceinline__ void insert10(u64 (&key)[KK], u64 k) {
    if (k > key[KK - 1]) {
#pragma unroll
        for (int j = KK - 1; j >= 1; --j)
            key[j] = (k > key[j - 1]) ? key[j - 1] : ((k > key[j]) ? k : key[j]);
        if (k > key[0]) key[0] = k;
    }
}

extern __shared__ __align__(16) unsigned char smem_raw[];

__global__ __launch_bounds__(BS) void dss_chunk_topk(
    const float* __restrict__ lprobs,
    const float* __restrict__ scores,
    const int*   __restrict__ step_ptr,
    int vocab, int sdim, int nc, int cs, int cap_f,
    u64* __restrict__ ws_keys)
{
    const int chunk = blockIdx.x;
    const int row   = blockIdx.y;
    const int tid   = threadIdx.x;
    const int lane  = tid & 63;
    const int step  = step_ptr[0];
    const float bias = scores[(size_t)row * sdim + (step - 1)];

    const int c0 = chunk * cs;
    int len = vocab - c0; if (len > cs) len = cs;      // >0 by construction
    const float* rp = lprobs + (size_t)row * vocab + c0;

    // LDS carve-up (cap_f multiple of 4 -> cand 16B aligned)
    float* lds_f = (float*)smem_raw;                       // cap_f floats
    u64*   cand  = (u64*)(smem_raw + (size_t)cap_f * 4);   // CAP u64
    float* smax  = (float*)(cand + CAP);                   // BS floats
    int*   s_cnt = (int*)(smax + BS);
    float* s_tau = (float*)(s_cnt + 1);

    // global dword misalignment; store into LDS shifted by a0 so float4 LDS
    // ops stay 16B-aligned. LDS index a0+j holds biased chunk element j.
    const int a0  = (int)(((uintptr_t)rp >> 2) & 3);
    int pre = (4 - a0) & 3; if (pre > len) pre = len;
    const float4* g4  = (const float4*)(rp + pre);
    const int nvec = (len - pre) >> 2;
    const int done = pre + 4 * nvec;
    const int rem  = len - done;
    float4* l4 = (float4*)(lds_f + a0 + pre);              // a0+pre is 0 or 4

    // ---- pass 1: HBM -> LDS (biased) + per-thread max
    float m = -INFINITY;
    if (tid < pre) { float v = rp[tid] + bias; lds_f[a0 + tid] = v; m = v; }
    for (int t = tid; t < nvec; t += BS) {
        float4 x = g4[t];
        x.x += bias; x.y += bias; x.z += bias; x.w += bias;
        l4[t] = x;
        m = fmaxf(m, fmaxf(fmaxf(x.x, x.y), fmaxf(x.z, x.w)));
    }
    if (tid < rem) { float v = rp[done + tid] + bias; lds_f[a0 + done + tid] = v; m = fmaxf(m, v); }

    smax[tid] = m;
    if (tid == 0) *s_cnt = 0;
    __syncthreads();

    // ---- tau: wave 0, 10th largest of 256 thread maxes
    if (tid < 64) {
        float a = smax[lane], b = smax[lane + 64], c = smax[lane + 128], d = smax[lane + 192];
        // sort {a,b,c,d} descending (5-comparator network)
        float t0;
        if (a < b) { t0 = a; a = b; b = t0; }
        if (c < d) { t0 = c; c = d; d = t0; }
        if (a < c) { t0 = a; a = c; c = t0; }
        if (b < d) { t0 = b; b = d; d = t0; }
        if (b < c) { t0 = b; b = c; c = t0; }
        float arr0 = a, arr1 = b, arr2 = c, arr3 = d;
        float tau = -INFINITY;
#pragma unroll
        for (int r = 0; r < KK; ++r) {
            float rv = arr0; int rl = lane;
#pragma unroll
            for (int o = 32; o >= 1; o >>= 1) {
                float ov = __shfl_xor(rv, o);
                int   ol = __shfl_xor(rl, o);
                if (ov > rv || (ov == rv && ol < rl)) { rv = ov; rl = ol; }
            }
            if (lane == rl) { arr0 = arr1; arr1 = arr2; arr2 = arr3; arr3 = -INFINITY; }
            tau = rv;
        }
        if (lane == 0) *s_tau = tau;
    }
    __syncthreads();
    const float tau = *s_tau;

    // ---- pass 2: filter from LDS (common path: 1 compare/element)
    auto app = [&](float v, int j) {           // j = chunk-local element index
        int p = atomicAdd(s_cnt, 1);
        if (p < CAP) cand[p] = ((u64)ford(v) << 32) | (uint32_t)~(c0 + j);
    };
    if (tid < pre) { float v = lds_f[a0 + tid]; if (v >= tau) app(v, tid); }
    for (int t = tid; t < nvec; t += BS) {
        float4 x = l4[t];
        int base = pre + 4 * t;
        if (x.x >= tau) app(x.x, base + 0);
        if (x.y >= tau) app(x.y, base + 1);
        if (x.z >= tau) app(x.z, base + 2);
        if (x.w >= tau) app(x.w, base + 3);
    }
    if (tid < rem) { float v = lds_f[a0 + done + tid]; if (v >= tau) app(v, done + tid); }
    __syncthreads();

    // ---- top-10 of survivors: wave 0 only
    if (tid < 64) {
        int n = *s_cnt; if (n > CAP) n = CAP;
        u64 key[KK];
#pragma unroll
        for (int j = 0; j < KK; ++j) key[j] = 0;
        for (int i = lane; i < n; i += 64) insert10(key, cand[i]);
        u64* outp = ws_keys + ((size_t)row * nc + chunk) * KK;
#pragma unroll
        for (int r = 0; r < KK; ++r) {
            u64 rv = key[0]; int rl = lane;
#pragma unroll
            for (int o = 32; o >= 1; o >>= 1) {
                u64 ov = __shfl_xor(rv, o);
                int ol = __shfl_xor(rl, o);
                if (ov > rv || (ov == rv && ol < rl)) { rv = ov; rl = ol; }
            }
            if (lane == rl) {
#pragma unroll
                for (int j = 0; j < KK - 1; ++j) key[j] = key[j + 1];
                key[KK - 1] = 0;
            }
            if (lane == 0) outp[r] = rv;
        }
    }
}

// fallback (whole-row, two global passes) for tiny ws_size — round-2-proven
__global__ __launch_bounds__(BS) void dss_row_topk(
    const float* __restrict__ lprobs,
    const float* __restrict__ scores,
    const int*   __restrict__ step_ptr,
    int vocab, int sdim,
    u64* __restrict__ ws_keys)
{
    const int row = blockIdx.x;
    const int tid = threadIdx.x;
    const int step = step_ptr[0];
    const float bias = scores[(size_t)row * sdim + (step - 1)];
    const float* rp = lprobs + (size_t)row * vocab;

    __shared__ u64  cand[FCAP];
    __shared__ u64  skey[BS * KK];
    __shared__ int  cnt;
    __shared__ float sh_tau;

    int pre = (4 - (int)(((uintptr_t)rp >> 2) & 3)) & 3;
    if (pre > vocab) pre = vocab;
    const float4* p4 = (const float4*)(rp + pre);
    const int nvec = (vocab - pre) >> 2;
    const int done = pre + 4 * nvec;
    const int rem  = vocab - done;

    float m = -INFINITY;
    if (tid < pre) m = rp[tid] + bias;
    for (int t = tid; t < nvec; t += BS) {
        float4 x = p4[t];
        m = fmaxf(m, fmaxf(fmaxf(x.x + bias, x.y + bias), fmaxf(x.z + bias, x.w + bias)));
    }
    if (tid < rem) m = fmaxf(m, rp[done + tid] + bias);

    skey[tid * KK] = ((u64)ford(m) << 32) | (uint32_t)~tid;
#pragma unroll
    for (int j = 1; j < KK; ++j) skey[tid * KK + j] = 0;
    if (tid == 0) cnt = 0;
    __syncthreads();
    for (int off = BS / 2; off >= 1; off >>= 1) {
        if (tid < off) {
            const int pa = tid * KK, pb = (tid + off) * KK;
            u64 mk[KK]; int ia = 0, ib = 0;
#pragma unroll
            for (int j = 0; j < KK; ++j) {
                u64 ka = skey[pa + ia], kb = skey[pb + ib];
                bool tA = (ka >= kb); mk[j] = tA ? ka : kb;
                if (tA) ++ia; else ++ib;
            }
#pragma unroll
            for (int j = 0; j < KK; ++j) skey[pa + j] = mk[j];
        }
        __syncthreads();
    }
    if (tid == 0) sh_tau = funord((uint32_t)(skey[9] >> 32));
    __syncthreads();
    const float tau = sh_tau;

    auto app = [&](float v, int i) {
        if (v >= tau) {
            int p = atomicAdd(&cnt, 1);
            if (p < FCAP) cand[p] = ((u64)ford(v) << 32) | (uint32_t)~i;
        }
    };
    if (tid < pre) app(rp[tid] + bias, tid);
    for (int t = tid; t < nvec; t += BS) {
        float4 x = p4[t];
        int base = pre + 4 * t;
        app(x.x + bias, base + 0); app(x.y + bias, base + 1);
        app(x.z + bias, base + 2); app(x.w + bias, base + 3);
    }
    if (tid < rem) app(rp[done + tid] + bias, done + tid);
    __syncthreads();

    const int n = (cnt < FCAP) ? cnt : FCAP;
    {
        u64 key[KK];
#pragma unroll
        for (int j = 0; j < KK; ++j) key[j] = 0;
        for (int i = tid; i < n; i += BS) insert10(key, cand[i]);
#pragma unroll
        for (int j = 0; j < KK; ++j) skey[tid * KK + j] = key[j];
    }
    __syncthreads();
    for (int off = BS / 2; off >= 1; off >>= 1) {
        if (tid < off) {
            const int pa = tid * KK, pb = (tid + off) * KK;
            u64 mk[KK]; int ia = 0, ib = 0;
#pragma unroll
            for (int j = 0; j < KK; ++j) {
                u64 ka = skey[pa + ia], kb = skey[pb + ib];
                bool tA = (ka >= kb); mk[j] = tA ? ka : kb;
                if (tA) ++ia; else ++ib;
            }
#pragma unroll
            for (int j = 0; j < KK; ++j) skey[pa + j] = mk[j];
        }
        __syncthreads();
    }
    if (tid < KK) ws_keys[(size_t)row * KK + tid] = skey[tid];
}

// per b: merge each row's nc*10 sorted candidates -> rank penalty -> final 50->10
__global__ __launch_bounds__(BEAM * 64) void dss_final(
    const u64* __restrict__ ws_keys,
    float* __restrict__ out, int bsz, int nc)
{
    const int b    = blockIdx.x;
    const int beam = threadIdx.x >> 6;     // 0..4
    const int lane = threadIdx.x & 63;

    __shared__ float s_pen[BEAM * KK];
    __shared__ int   s_idx[BEAM * KK];

    const int ncand = nc * KK;             // <= 80
    const u64* kp = ws_keys + (size_t)(b * BEAM + beam) * ncand;
    u64 c0 = (lane < ncand) ? kp[lane] : 0;
    u64 c1 = (lane + 64 < ncand) ? kp[lane + 64] : 0;

#pragma unroll
    for (int r = 0; r < KK; ++r) {
        u64 my = (c0 > c1) ? c0 : c1;
        u64 rv = my; int rl = lane;
#pragma unroll
        for (int o = 32; o >= 1; o >>= 1) {
            u64 ov = __shfl_xor(rv, o);
            int ol = __shfl_xor(rl, o);
            if (ov > rv || (ov == rv && ol < rl)) { rv = ov; rl = ol; }
        }
        if (lane == rl) { if (c0 == rv) c0 = 0; else c1 = 0; }
        if (lane == 0) {
            s_pen[beam * KK + r] = funord((uint32_t)(rv >> 32)) - 0.5f * (float)(r + 1);
            s_idx[beam * KK + r] = (int)~(uint32_t)rv;
        }
    }
    __syncthreads();

    if (threadIdx.x < 64) {
        float v = -INFINITY; int vidx = 0;
        if (lane < BEAM * KK) { v = s_pen[lane]; vidx = s_idx[lane]; }
        float* out_scores  = out;
        float* out_indices = out + (size_t)bsz * KK;
        float* out_beams   = out + 2 * (size_t)bsz * KK;
        for (int o = 0; o < KK; ++o) {
            float rv = v; int rp = lane;   // tie -> lowest flat pos (jax top_k)
#pragma unroll
            for (int off = 32; off >= 1; off >>= 1) {
                float ov = __shfl_xor(rv, off);
                int   op = __shfl_xor(rp, off);
                if (ov > rv || (ov == rv && op < rp)) { rv = ov; rp = op; }
            }
            int widx = __shfl(vidx, rp);
            if (lane == 0) {
                out_scores [b * KK + o] = rv;
                out_indices[b * KK + o] = (float)widx;
                out_beams  [b * KK + o] = (float)(rp / KK);
            }
            if (lane == rp) v = -INFINITY;
        }
    }
}

extern "C" void kernel_launch(void* const* d_in, const int* in_sizes, int n_in,
                              void* d_out, int out_size, void* d_ws, size_t ws_size,
                              hipStream_t stream)
{
    const float* lprobs = (const float*)d_in[0];
    const float* scores = (const float*)d_in[1];
    const int*   step   = (const int*)d_in[2];

    const int bsz   = 128;
    const int rows  = bsz * BEAM;                 // 640
    const int vocab = in_sizes[0] / rows;         // 50257
    const int sdim  = in_sizes[1] / rows;         // 10

    u64* ws_keys = (u64*)d_ws;

    int nc = 8;
    if (ws_size < (size_t)rows * 8 * KK * sizeof(u64)) nc = 4;
    if (ws_size < (size_t)rows * 4 * KK * sizeof(u64)) nc = 1;

    if (nc > 1) {
        const int cs = (vocab + nc - 1) / nc;
        const int cap_f = (cs + 3 + 3) & ~3;       // a0-shift slack, round to 4
        const size_t smem = (size_t)cap_f * 4 + (size_t)CAP * 8 + BS * 4 + 16;
        dss_chunk_topk<<<dim3(nc, rows), BS, smem, stream>>>(
            lprobs, scores, step, vocab, sdim, nc, cs, cap_f, ws_keys);
    } else {
        dss_row_topk<<<rows, BS, 0, stream>>>(lprobs, scores, step, vocab, sdim, ws_keys);
    }
    dss_final<<<bsz, BEAM * 64, 0, stream>>>(ws_keys, (float*)d_out, bsz, nc);
}

// Round 4
// 211.880 us; speedup vs baseline: 1.1893x; 1.1893x over previous
//
#include <hip/hip_runtime.h>
#include <hip/hip_bf16.h>
#include <math.h>
#include <stdint.h>

// DiverseSiblingsSearch (lprobs (128,5,50257) f32, scores (128,5,10) f32, step=10)
//   lp = lprobs + scores[:,:,step-1,None]  (bias added BEFORE ordering, as reference)
//   per (b,beam): top-10 of lp over vocab; penalty -0.5*(rank+1); per b: top-10 of 50.
// Outputs concat as float32 values: scores[1280] | indices[1280] | beams[1280]
//
// Kernel 1 (dss_chunk_topk), grid (nc=8 chunks, 640 rows), 256 thr:
//   - each thread holds its 28 chunk elements (biased) in 7 float4 REGISTERS
//     (single HBM read; no LDS staging — round-3 lesson)
//   - tau = 10th largest of wave 0's 64 thread-maxes via 21-step shfl bitonic
//     (register-only, no barrier; valid lower bound on chunk's 10th-largest:
//      10 distinct threads each contribute >=1 element >= tau)
//   - filter from registers (1 cmp/elem common path), append survivors to LDS
//     (expected ~40, key = ford(val)<<32 | ~idx -> value desc, index asc = jax order)
//   - extract top-10: n<=64 -> 64-lane u64 bitonic sort, lanes 0..9 write ws;
//     n>64 (pathological ties) -> insert10 + 10-round argmax butterfly
// Kernel 2 (dss_final): per b: merge 8 sorted 10-lists/beam -> row top-10 ->
//   rank penalty -> final top-10 of 50 (flat-pos tie, matches jax).

#define BS    256
#define KK    10
#define BEAM  5
#define CS    7168       // chunk elems = BS * NSLOT * 4
#define NSLOT 7
#define CAP   2048       // survivor buffer (expected ~40; hard guard below)
#define FCAP  2048

typedef unsigned long long u64;

// monotone float <-> uint map (no NaNs in log_softmax output)
__device__ __forceinline__ uint32_t ford(float x) {
    uint32_t u = __float_as_uint(x);
    return (u & 0x80000000u) ? ~u : (u | 0x80000000u);
}
__device__ __forceinline__ float funord(uint32_t u) {
    return __uint_as_float((u & 0x80000000u) ? (u & 0x7fffffffu) : ~u);
}

// guarded sorted-desc insert (common path: 1 compare)
__device__ __forceinline__ void insert10(u64 (&key)[KK], u64 k) {
    if (k > key[KK - 1]) {
#pragma unroll
        for (int j = KK - 1; j >= 1; --j)
            key[j] = (k > key[j - 1]) ? key[j - 1] : ((k > key[j]) ? k : key[j]);
        if (k > key[0]) key[0] = k;
    }
}

__global__ __launch_bounds__(BS) void dss_chunk_topk(
    const float* __restrict__ lprobs,
    const float* __restrict__ scores,
    const int*   __restrict__ step_ptr,
    int vocab, int sdim, int nc,
    u64* __restrict__ ws_keys)
{
    const int chunk = blockIdx.x;
    const int row   = blockIdx.y;
    const int tid   = threadIdx.x;
    const int lane  = tid & 63;
    const int step  = step_ptr[0];
    const float bias = scores[(size_t)row * sdim + (step - 1)];

    const int c0 = chunk * CS;
    int len = vocab - c0; if (len > CS) len = CS;
    const float* cp = lprobs + (size_t)row * vocab + c0;

    __shared__ u64  cand[CAP];
    __shared__ int  s_cnt;
    __shared__ float s_tau;

    // CS%4==0 -> every chunk of a row has the row's dword misalignment
    int pre = (4 - (int)(((uintptr_t)cp >> 2) & 3)) & 3;
    if (pre > len) pre = len;
    const float4* g4 = (const float4*)(cp + pre);
    const int nvec = (len - pre) >> 2;
    const int done = pre + 4 * nvec;
    const int rem  = len - done;

    // ---- single pass: load chunk into registers (biased) + per-thread max
    float4 v[NSLOT];
    float m = -INFINITY;
#pragma unroll
    for (int i = 0; i < NSLOT; ++i) {
        int idx = tid + (i << 8);
        if (idx < nvec) {
            float4 x = g4[idx];
            x.x += bias; x.y += bias; x.z += bias; x.w += bias;
            v[i] = x;
            m = fmaxf(m, fmaxf(fmaxf(x.x, x.y), fmaxf(x.z, x.w)));
        } else {
            v[i].x = -INFINITY; v[i].y = -INFINITY; v[i].z = -INFINITY; v[i].w = -INFINITY;
        }
    }
    // boundary leftovers: pre -> threads 0..2, rem -> threads 4..6 (one each)
    float xv = -INFINITY; int xi = -1;
    if (tid < pre)                        { xi = tid;            xv = cp[xi] + bias; }
    else if (tid >= 4 && tid < 4 + rem)   { xi = done + tid - 4; xv = cp[xi] + bias; }
    m = fmaxf(m, xv);

    if (tid == 0) s_cnt = 0;

    // ---- tau: wave 0 bitonic-sorts its own 64 maxes (desc); lane 9 = 10th
    if (tid < 64) {
        float s = m;
#pragma unroll
        for (int k2 = 2; k2 <= 64; k2 <<= 1) {
#pragma unroll
            for (int j = k2 >> 1; j >= 1; j >>= 1) {
                float p = __shfl_xor(s, j);
                bool lower   = (lane & j) == 0;
                bool dirDesc = (lane & k2) == 0;
                s = (dirDesc == lower) ? fmaxf(s, p) : fminf(s, p);
            }
        }
        if (lane == 9) s_tau = s;
    }
    __syncthreads();
    const float tau = s_tau;

    // ---- filter from registers (common path: 1 compare/element)
    auto app = [&](float x, int j) {      // j = chunk-local index (validated)
        if (j < len) {
            int p = atomicAdd(&s_cnt, 1);
            if (p < CAP) cand[p] = ((u64)ford(x) << 32) | (uint32_t)~(c0 + j);
        }
    };
#pragma unroll
    for (int i = 0; i < NSLOT; ++i) {
        int base = pre + ((tid + (i << 8)) << 2);
        if (v[i].x >= tau) app(v[i].x, base + 0);
        if (v[i].y >= tau) app(v[i].y, base + 1);
        if (v[i].z >= tau) app(v[i].z, base + 2);
        if (v[i].w >= tau) app(v[i].w, base + 3);
    }
    if (xi >= 0 && xv >= tau) app(xv, xi);
    __syncthreads();

    // ---- extract top-10 of survivors (wave 0)
    if (tid < 64) {
        int n = s_cnt; if (n > CAP) n = CAP;
        u64* outp = ws_keys + ((size_t)row * nc + chunk) * KK;
        if (n <= 64) {
            u64 k = (lane < n) ? cand[lane] : 0;
#pragma unroll
            for (int k2 = 2; k2 <= 64; k2 <<= 1) {
#pragma unroll
                for (int j = k2 >> 1; j >= 1; j >>= 1) {
                    u64 p = __shfl_xor(k, j);
                    bool lower   = (lane & j) == 0;
                    bool dirDesc = (lane & k2) == 0;
                    bool wantMax = (dirDesc == lower);
                    k = wantMax ? (k > p ? k : p) : (k < p ? k : p);
                }
            }
            if (lane < KK) outp[lane] = k;
        } else {
            u64 key[KK];
#pragma unroll
            for (int j = 0; j < KK; ++j) key[j] = 0;
            for (int i = lane; i < n; i += 64) insert10(key, cand[i]);
#pragma unroll
            for (int r = 0; r < KK; ++r) {
                u64 rv = key[0]; int rl = lane;
#pragma unroll
                for (int o = 32; o >= 1; o >>= 1) {
                    u64 ov = __shfl_xor(rv, o);
                    int ol = __shfl_xor(rl, o);
                    if (ov > rv || (ov == rv && ol < rl)) { rv = ov; rl = ol; }
                }
                if (lane == rl) {
#pragma unroll
                    for (int j = 0; j < KK - 1; ++j) key[j] = key[j + 1];
                    key[KK - 1] = 0;
                }
                if (lane == 0) outp[r] = rv;
            }
        }
    }
}

// fallback (whole-row, two global passes) for tiny ws_size — round-2-proven
__global__ __launch_bounds__(BS) void dss_row_topk(
    const float* __restrict__ lprobs,
    const float* __restrict__ scores,
    const int*   __restrict__ step_ptr,
    int vocab, int sdim,
    u64* __restrict__ ws_keys)
{
    const int row = blockIdx.x;
    const int tid = threadIdx.x;
    const int step = step_ptr[0];
    const float bias = scores[(size_t)row * sdim + (step - 1)];
    const float* rp = lprobs + (size_t)row * vocab;

    __shared__ u64  cand[FCAP];
    __shared__ u64  skey[BS * KK];
    __shared__ int  cnt;
    __shared__ float sh_tau;

    int pre = (4 - (int)(((uintptr_t)rp >> 2) & 3)) & 3;
    if (pre > vocab) pre = vocab;
    const float4* p4 = (const float4*)(rp + pre);
    const int nvec = (vocab - pre) >> 2;
    const int done = pre + 4 * nvec;
    const int rem  = vocab - done;

    float m = -INFINITY;
    if (tid < pre) m = rp[tid] + bias;
    for (int t = tid; t < nvec; t += BS) {
        float4 x = p4[t];
        m = fmaxf(m, fmaxf(fmaxf(x.x + bias, x.y + bias), fmaxf(x.z + bias, x.w + bias)));
    }
    if (tid < rem) m = fmaxf(m, rp[done + tid] + bias);

    skey[tid * KK] = ((u64)ford(m) << 32) | (uint32_t)~tid;
#pragma unroll
    for (int j = 1; j < KK; ++j) skey[tid * KK + j] = 0;
    if (tid == 0) cnt = 0;
    __syncthreads();
    for (int off = BS / 2; off >= 1; off >>= 1) {
        if (tid < off) {
            const int pa = tid * KK, pb = (tid + off) * KK;
            u64 mk[KK]; int ia = 0, ib = 0;
#pragma unroll
            for (int j = 0; j < KK; ++j) {
                u64 ka = skey[pa + ia], kb = skey[pb + ib];
                bool tA = (ka >= kb); mk[j] = tA ? ka : kb;
                if (tA) ++ia; else ++ib;
            }
#pragma unroll
            for (int j = 0; j < KK; ++j) skey[pa + j] = mk[j];
        }
        __syncthreads();
    }
    if (tid == 0) sh_tau = funord((uint32_t)(skey[9] >> 32));
    __syncthreads();
    const float tau = sh_tau;

    auto app = [&](float x, int i) {
        if (x >= tau) {
            int p = atomicAdd(&cnt, 1);
            if (p < FCAP) cand[p] = ((u64)ford(x) << 32) | (uint32_t)~i;
        }
    };
    if (tid < pre) app(rp[tid] + bias, tid);
    for (int t = tid; t < nvec; t += BS) {
        float4 x = p4[t];
        int base = pre + 4 * t;
        app(x.x + bias, base + 0); app(x.y + bias, base + 1);
        app(x.z + bias, base + 2); app(x.w + bias, base + 3);
    }
    if (tid < rem) app(rp[done + tid] + bias, done + tid);
    __syncthreads();

    const int n = (cnt < FCAP) ? cnt : FCAP;
    {
        u64 key[KK];
#pragma unroll
        for (int j = 0; j < KK; ++j) key[j] = 0;
        for (int i = tid; i < n; i += BS) insert10(key, cand[i]);
#pragma unroll
        for (int j = 0; j < KK; ++j) skey[tid * KK + j] = key[j];
    }
    __syncthreads();
    for (int off = BS / 2; off >= 1; off >>= 1) {
        if (tid < off) {
            const int pa = tid * KK, pb = (tid + off) * KK;
            u64 mk[KK]; int ia = 0, ib = 0;
#pragma unroll
            for (int j = 0; j < KK; ++j) {
                u64 ka = skey[pa + ia], kb = skey[pb + ib];
                bool tA = (ka >= kb); mk[j] = tA ? ka : kb;
                if (tA) ++ia; else ++ib;
            }
#pragma unroll
            for (int j = 0; j < KK; ++j) skey[pa + j] = mk[j];
        }
        __syncthreads();
    }
    if (tid < KK) ws_keys[(size_t)row * KK + tid] = skey[tid];
}

// per b: merge each row's nc*10 sorted candidates -> rank penalty -> final 50->10
__global__ __launch_bounds__(BEAM * 64) void dss_final(
    const u64* __restrict__ ws_keys,
    float* __restrict__ out, int bsz, int nc)
{
    const int b    = blockIdx.x;
    const int beam = threadIdx.x >> 6;     // 0..4
    const int lane = threadIdx.x & 63;

    __shared__ float s_pen[BEAM * KK];
    __shared__ int   s_idx[BEAM * KK];

    const int ncand = nc * KK;             // <= 80
    const u64* kp = ws_keys + (size_t)(b * BEAM + beam) * ncand;
    u64 c0 = (lane < ncand) ? kp[lane] : 0;
    u64 c1 = (lane + 64 < ncand) ? kp[lane + 64] : 0;

#pragma unroll
    for (int r = 0; r < KK; ++r) {
        u64 my = (c0 > c1) ? c0 : c1;
        u64 rv = my; int rl = lane;
#pragma unroll
        for (int o = 32; o >= 1; o >>= 1) {
            u64 ov = __shfl_xor(rv, o);
            int ol = __shfl_xor(rl, o);
            if (ov > rv || (ov == rv && ol < rl)) { rv = ov; rl = ol; }
        }
        if (lane == rl) { if (c0 == rv) c0 = 0; else c1 = 0; }
        if (lane == 0) {
            s_pen[beam * KK + r] = funord((uint32_t)(rv >> 32)) - 0.5f * (float)(r + 1);
            s_idx[beam * KK + r] = (int)~(uint32_t)rv;
        }
    }
    __syncthreads();

    if (threadIdx.x < 64) {
        float v = -INFINITY; int vidx = 0;
        if (lane < BEAM * KK) { v = s_pen[lane]; vidx = s_idx[lane]; }
        float* out_scores  = out;
        float* out_indices = out + (size_t)bsz * KK;
        float* out_beams   = out + 2 * (size_t)bsz * KK;
        for (int o = 0; o < KK; ++o) {
            float rv = v; int rp = lane;   // tie -> lowest flat pos (jax top_k)
#pragma unroll
            for (int off = 32; off >= 1; off >>= 1) {
                float ov = __shfl_xor(rv, off);
                int   op = __shfl_xor(rp, off);
                if (ov > rv || (ov == rv && op < rp)) { rv = ov; rp = op; }
            }
            int widx = __shfl(vidx, rp);
            if (lane == 0) {
                out_scores [b * KK + o] = rv;
                out_indices[b * KK + o] = (float)widx;
                out_beams  [b * KK + o] = (float)(rp / KK);
            }
            if (lane == rp) v = -INFINITY;
        }
    }
}

extern "C" void kernel_launch(void* const* d_in, const int* in_sizes, int n_in,
                              void* d_out, int out_size, void* d_ws, size_t ws_size,
                              hipStream_t stream)
{
    const float* lprobs = (const float*)d_in[0];
    const float* scores = (const float*)d_in[1];
    const int*   step   = (const int*)d_in[2];

    const int bsz   = 128;
    const int rows  = bsz * BEAM;                 // 640
    const int vocab = in_sizes[0] / rows;         // 50257
    const int sdim  = in_sizes[1] / rows;         // 10

    u64* ws_keys = (u64*)d_ws;

    int nc = (vocab + CS - 1) / CS;               // 8
    if (ws_size < (size_t)rows * nc * KK * sizeof(u64)) nc = 1;

    if (nc > 1) {
        dss_chunk_topk<<<dim3(nc, rows), BS, 0, stream>>>(
            lprobs, scores, step, vocab, sdim, nc, ws_keys);
    } else {
        dss_row_topk<<<rows, BS, 0, stream>>>(lprobs, scores, step, vocab, sdim, ws_keys);
    }
    dss_final<<<bsz, BEAM * 64, 0, stream>>>(ws_keys, (float*)d_out, bsz, nc);
}

// Round 5
// 200.191 us; speedup vs baseline: 1.2588x; 1.0584x over previous
//
#include <hip/hip_runtime.h>
#include <hip/hip_bf16.h>
#include <math.h>
#include <stdint.h>

// DiverseSiblingsSearch (lprobs (128,5,50257) f32, scores (128,5,10) f32, step=10)
//   lp = lprobs + scores[:,:,step-1,None]  (bias added BEFORE ordering, as reference)
//   per (b,beam): top-10 of lp over vocab; penalty -0.5*(rank+1); per b: top-10 of 50.
// Outputs concat as float32 values: scores[1280] | indices[1280] | beams[1280]
//
// Round-5 structure (lesson from r3/r4: dependent-shfl bitonic tails starve the
// memory pipe — blocks sat in ~6-8k-cycle wave0-serial sections, duty cycle of
// load issue ~20%, 1.9 TB/s effective):
//   Kernel 1, grid (8 chunks, 640 rows), 256 thr, register-resident chunk:
//     - 28 biased elems/thread in 7 float4 regs (one HBM read, no staging)
//     - tau PER WAVE: rank own max among wave's 64 maxes via 64 independent
//       v_readlane+cmp (no LDS, no barrier, no dependent chain); rank-9 lane
//       broadcasts tau. Valid bound: any chunk-top-10 elem in wave w is in
//       wave w's top-10, and tau_w <= wave w's 10th-largest elem. >=10
//       survivors/wave guaranteed.
//     - filter from regs (1 cmp/elem) -> LDS append (expected ~40 total)
//     - extraction: 256-thread rank-select (broadcast LDS reads, independent,
//       ~40 iters); keys unique -> ranks exact; rank<10 writes ws directly.
//   Kernel 2 (dss_final): rank-select twice (per-beam 80 -> 10 w/ penalty,
//   then 50 -> 10 with flat-pos tie-break = jax order).

#define BS    256
#define KK    10
#define BEAM  5
#define CS    7168       // chunk elems = BS * NSLOT * 4
#define NSLOT 7
#define CAP   1024       // survivor buffer (expected ~40/block)
#define FCAP  2048

typedef unsigned long long u64;

// monotone float <-> uint map (no NaNs in log_softmax output)
__device__ __forceinline__ uint32_t ford(float x) {
    uint32_t u = __float_as_uint(x);
    return (u & 0x80000000u) ? ~u : (u | 0x80000000u);
}
__device__ __forceinline__ float funord(uint32_t u) {
    return __uint_as_float((u & 0x80000000u) ? (u & 0x7fffffffu) : ~u);
}

// guarded sorted-desc insert (fallback kernel only)
__device__ __forceinline__ void insert10(u64 (&key)[KK], u64 k) {
    if (k > key[KK - 1]) {
#pragma unroll
        for (int j = KK - 1; j >= 1; --j)
            key[j] = (k > key[j - 1]) ? key[j - 1] : ((k > key[j]) ? k : key[j]);
        if (k > key[0]) key[0] = k;
    }
}

__global__ __launch_bounds__(BS) void dss_chunk_topk(
    const float* __restrict__ lprobs,
    const float* __restrict__ scores,
    const int*   __restrict__ step_ptr,
    int vocab, int sdim, int nc,
    u64* __restrict__ ws_keys)
{
    const int chunk = blockIdx.x;
    const int row   = blockIdx.y;
    const int tid   = threadIdx.x;
    const int lane  = tid & 63;
    const int step  = step_ptr[0];
    const float bias = scores[(size_t)row * sdim + (step - 1)];

    const int c0 = chunk * CS;
    int len = vocab - c0; if (len > CS) len = CS;
    const float* cp = lprobs + (size_t)row * vocab + c0;

    __shared__ u64  cand[CAP];
    __shared__ int  s_cnt;

    // CS%4==0 -> every chunk of a row shares the row's dword misalignment
    int pre = (4 - (int)(((uintptr_t)cp >> 2) & 3)) & 3;
    if (pre > len) pre = len;
    const float4* g4 = (const float4*)(cp + pre);
    const int nvec = (len - pre) >> 2;
    const int done = pre + 4 * nvec;
    const int rem  = len - done;

    // ---- single pass: chunk into registers (biased) + per-thread max
    float4 v[NSLOT];
    float m = -INFINITY;
#pragma unroll
    for (int i = 0; i < NSLOT; ++i) {
        int idx = tid + (i << 8);
        if (idx < nvec) {
            float4 x = g4[idx];
            x.x += bias; x.y += bias; x.z += bias; x.w += bias;
            v[i] = x;
            m = fmaxf(m, fmaxf(fmaxf(x.x, x.y), fmaxf(x.z, x.w)));
        } else {
            v[i].x = -INFINITY; v[i].y = -INFINITY; v[i].z = -INFINITY; v[i].w = -INFINITY;
        }
    }
    // boundary leftovers: pre -> threads 0..2, rem -> threads 4..6 (one each)
    float xv = -INFINITY; int xi = -1;
    if (tid < pre)                        { xi = tid;            xv = cp[xi] + bias; }
    else if (tid >= 4 && tid < 4 + rem)   { xi = done + tid - 4; xv = cp[xi] + bias; }
    m = fmaxf(m, xv);

    if (tid == 0) s_cnt = 0;

    // ---- per-wave tau: rank own max among the wave's 64 maxes (independent
    // readlane+cmp ops, pipelineable; ties by lane -> ranks are a permutation)
    int r = 0;
    const int mb = __float_as_int(m);
    for (int j = 0; j < 64; ++j) {
        float vj = __int_as_float(__builtin_amdgcn_readlane(mb, j));
        r += (vj > m || (vj == m && j < lane)) ? 1 : 0;
    }
    u64 msk = __ballot(r == 9);                  // exactly one lane
    int src = __ffsll((long long)msk) - 1;
    const float tau = __int_as_float(__builtin_amdgcn_readlane(mb, src));

    __syncthreads();                             // s_cnt=0 visible

    // ---- filter from registers (common path: 1 compare/element)
    auto app = [&](float x, int j) {             // j = chunk-local index
        if (j < len) {
            int p = atomicAdd(&s_cnt, 1);
            if (p < CAP) cand[p] = ((u64)ford(x) << 32) | (uint32_t)~(c0 + j);
        }
    };
#pragma unroll
    for (int i = 0; i < NSLOT; ++i) {
        int base = pre + ((tid + (i << 8)) << 2);
        if (v[i].x >= tau) app(v[i].x, base + 0);
        if (v[i].y >= tau) app(v[i].y, base + 1);
        if (v[i].z >= tau) app(v[i].z, base + 2);
        if (v[i].w >= tau) app(v[i].w, base + 3);
    }
    if (xi >= 0 && xv >= tau) app(xv, xi);
    __syncthreads();

    // ---- extraction: 256-thread rank-select (keys unique -> exact)
    int n = s_cnt; if (n > CAP) n = CAP;
    u64* outp = ws_keys + ((size_t)row * nc + chunk) * KK;
    for (int t = tid; t < n; t += BS) {
        u64 k = cand[t];
        int rk = 0;
        for (int j = 0; j < n; ++j) rk += (cand[j] > k) ? 1 : 0;   // broadcast reads
        if (rk < KK) outp[rk] = k;
    }
}

// fallback (whole-row, two global passes) for tiny ws_size — round-2-proven
__global__ __launch_bounds__(BS) void dss_row_topk(
    const float* __restrict__ lprobs,
    const float* __restrict__ scores,
    const int*   __restrict__ step_ptr,
    int vocab, int sdim,
    u64* __restrict__ ws_keys)
{
    const int row = blockIdx.x;
    const int tid = threadIdx.x;
    const int step = step_ptr[0];
    const float bias = scores[(size_t)row * sdim + (step - 1)];
    const float* rp = lprobs + (size_t)row * vocab;

    __shared__ u64  cand[FCAP];
    __shared__ u64  skey[BS * KK];
    __shared__ int  cnt;
    __shared__ float sh_tau;

    int pre = (4 - (int)(((uintptr_t)rp >> 2) & 3)) & 3;
    if (pre > vocab) pre = vocab;
    const float4* p4 = (const float4*)(rp + pre);
    const int nvec = (vocab - pre) >> 2;
    const int done = pre + 4 * nvec;
    const int rem  = vocab - done;

    float m = -INFINITY;
    if (tid < pre) m = rp[tid] + bias;
    for (int t = tid; t < nvec; t += BS) {
        float4 x = p4[t];
        m = fmaxf(m, fmaxf(fmaxf(x.x + bias, x.y + bias), fmaxf(x.z + bias, x.w + bias)));
    }
    if (tid < rem) m = fmaxf(m, rp[done + tid] + bias);

    skey[tid * KK] = ((u64)ford(m) << 32) | (uint32_t)~tid;
#pragma unroll
    for (int j = 1; j < KK; ++j) skey[tid * KK + j] = 0;
    if (tid == 0) cnt = 0;
    __syncthreads();
    for (int off = BS / 2; off >= 1; off >>= 1) {
        if (tid < off) {
            const int pa = tid * KK, pb = (tid + off) * KK;
            u64 mk[KK]; int ia = 0, ib = 0;
#pragma unroll
            for (int j = 0; j < KK; ++j) {
                u64 ka = skey[pa + ia], kb = skey[pb + ib];
                bool tA = (ka >= kb); mk[j] = tA ? ka : kb;
                if (tA) ++ia; else ++ib;
            }
#pragma unroll
            for (int j = 0; j < KK; ++j) skey[pa + j] = mk[j];
        }
        __syncthreads();
    }
    if (tid == 0) sh_tau = funord((uint32_t)(skey[9] >> 32));
    __syncthreads();
    const float tau = sh_tau;

    auto app = [&](float x, int i) {
        if (x >= tau) {
            int p = atomicAdd(&cnt, 1);
            if (p < FCAP) cand[p] = ((u64)ford(x) << 32) | (uint32_t)~i;
        }
    };
    if (tid < pre) app(rp[tid] + bias, tid);
    for (int t = tid; t < nvec; t += BS) {
        float4 x = p4[t];
        int base = pre + 4 * t;
        app(x.x + bias, base + 0); app(x.y + bias, base + 1);
        app(x.z + bias, base + 2); app(x.w + bias, base + 3);
    }
    if (tid < rem) app(rp[done + tid] + bias, done + tid);
    __syncthreads();

    const int n = (cnt < FCAP) ? cnt : FCAP;
    {
        u64 key[KK];
#pragma unroll
        for (int j = 0; j < KK; ++j) key[j] = 0;
        for (int i = tid; i < n; i += BS) insert10(key, cand[i]);
#pragma unroll
        for (int j = 0; j < KK; ++j) skey[tid * KK + j] = key[j];
    }
    __syncthreads();
    for (int off = BS / 2; off >= 1; off >>= 1) {
        if (tid < off) {
            const int pa = tid * KK, pb = (tid + off) * KK;
            u64 mk[KK]; int ia = 0, ib = 0;
#pragma unroll
            for (int j = 0; j < KK; ++j) {
                u64 ka = skey[pa + ia], kb = skey[pb + ib];
                bool tA = (ka >= kb); mk[j] = tA ? ka : kb;
                if (tA) ++ia; else ++ib;
            }
#pragma unroll
            for (int j = 0; j < KK; ++j) skey[pa + j] = mk[j];
        }
        __syncthreads();
    }
    if (tid < KK) ws_keys[(size_t)row * KK + tid] = skey[tid];
}

// per b: rank-select per beam (nc*10 -> 10, apply penalty), then 50 -> 10
__global__ __launch_bounds__(512) void dss_final(
    const u64* __restrict__ ws_keys,
    float* __restrict__ out, int bsz, int nc)
{
    const int b = blockIdx.x;
    const int t = threadIdx.x;
    const int NC  = nc * KK;            // <= 80
    const int tot = BEAM * NC;          // <= 400

    __shared__ u64  kbuf[BEAM * KK * 8];
    __shared__ float pen[BEAM * KK];
    __shared__ int   pidx[BEAM * KK];

    for (int i = t; i < tot; i += 512) kbuf[i] = ws_keys[(size_t)b * tot + i];
    __syncthreads();

    // phase 1: per-beam top-10 via rank-select (keys unique within a beam)
    if (t < tot) {
        int beam = t / NC;
        u64 k = kbuf[t];
        const u64* kb = kbuf + beam * NC;
        int r = 0;
        for (int j = 0; j < NC; ++j) r += (kb[j] > k) ? 1 : 0;
        if (r < KK) {
            pen [beam * KK + r] = funord((uint32_t)(k >> 32)) - 0.5f * (float)(r + 1);
            pidx[beam * KK + r] = (int)~(uint32_t)k;
        }
    }
    __syncthreads();

    // phase 2: top-10 of 50, ties -> lowest flat position (jax top_k order)
    if (t < BEAM * KK) {
        float p = pen[t];
        int r = 0;
        for (int j = 0; j < BEAM * KK; ++j) {
            float q = pen[j];
            r += (q > p || (q == p && j < t)) ? 1 : 0;
        }
        if (r < KK) {
            out[              b * KK + r] = p;
            out[(size_t)bsz * KK     + b * KK + r] = (float)pidx[t];
            out[(size_t)2 * bsz * KK + b * KK + r] = (float)(t / KK);
        }
    }
}

extern "C" void kernel_launch(void* const* d_in, const int* in_sizes, int n_in,
                              void* d_out, int out_size, void* d_ws, size_t ws_size,
                              hipStream_t stream)
{
    const float* lprobs = (const float*)d_in[0];
    const float* scores = (const float*)d_in[1];
    const int*   step   = (const int*)d_in[2];

    const int bsz   = 128;
    const int rows  = bsz * BEAM;                 // 640
    const int vocab = in_sizes[0] / rows;         // 50257
    const int sdim  = in_sizes[1] / rows;         // 10

    u64* ws_keys = (u64*)d_ws;

    int nc = (vocab + CS - 1) / CS;               // 8
    if (nc > 8) nc = 8;                           // kbuf sizing bound
    if (ws_size < (size_t)rows * nc * KK * sizeof(u64)) nc = 1;

    if (nc > 1) {
        dss_chunk_topk<<<dim3(nc, rows), BS, 0, stream>>>(
            lprobs, scores, step, vocab, sdim, nc, ws_keys);
    } else {
        dss_row_topk<<<rows, BS, 0, stream>>>(lprobs, scores, step, vocab, sdim, ws_keys);
    }
    dss_final<<<bsz, 512, 0, stream>>>(ws_keys, (float*)d_out, bsz, nc);
}